// Round 11
// baseline (184.254 us; speedup 1.0000x reference)
//
#include <hip/hip_runtime.h>
#include <hip/hip_fp16.h>
#include <math.h>

// GCN 3-layer forward. Padded-CSR gather (f16 tables), MFMA GEMMs, fused gather+GEMM.
// out[i] = dis[i]*(hs[i] + sum_{src in N(i)} hs[src]) + b,  hs = (act(X)@W)*dis[row]

static inline size_t align256(size_t x) { return (x + 255) & ~(size_t)255; }

#define NBLK 1024         // blocks for bucket pass (wave-latency-bound: more waves)
#define MAXB 6144         // fixed bucket capacity (mean 4092, sigma 64 -> +32 sigma)

using f16x8 = __attribute__((ext_vector_type(8))) _Float16;
using f32x4 = __attribute__((ext_vector_type(4))) float;
union U16 { uint4 u; f16x8 h; };

__device__ __forceinline__ __half2 u2h(unsigned u) { union { unsigned u; __half2 h; } t; t.u = u; return t.h; }
__device__ __forceinline__ unsigned h2u(__half2 h) { union { unsigned u; __half2 h; } t; t.h = h; return t.u; }

// exclusive scan of one value per thread across the block (256 threads)
template<int NW>
__device__ __forceinline__ int block_excl_scan(int v, int t, int* wsum) {
    int lane = t & 63, w = t >> 6;
    int incl = v;
    #pragma unroll
    for (int off = 1; off < 64; off <<= 1) {
        int u = __shfl_up(incl, off, 64);
        if (lane >= off) incl += u;
    }
    if (lane == 63) wsum[w] = incl;
    __syncthreads();
    if (t == 0) {
        int acc = 0;
        #pragma unroll
        for (int i = 0; i < NW; ++i) { int x = wsum[i]; wsum[i] = acc; acc += x; }
    }
    __syncthreads();
    return incl - v + wsum[w];
}

// ---------- pass 0: weight prep (blocks 0..2) + zero counters (block 3) ----------
__global__ void k_zero(const float* __restrict__ W1, const float* __restrict__ W2,
                       const float* __restrict__ W3, uint4* __restrict__ Wh1,
                       uint4* __restrict__ Wh2, uint4* __restrict__ Wh3,
                       int* __restrict__ bucketCnt, int* __restrict__ degHist, int nb) {
    int b = blockIdx.x;
    int t = threadIdx.x;
    if (b == 3) {
        for (int i = t; i < nb * 16; i += 512) bucketCnt[i] = 0;
        if (t < 64) degHist[t] = 0;
        return;
    }
    const float* W = (b == 0) ? W1 : (b == 1) ? W2 : W3;
    uint4* Wh = (b == 0) ? Wh1 : (b == 1) ? Wh2 : Wh3;
    int dout = (b == 2) ? 40 : 64, ntc = (b == 2) ? 3 : 4;
    int total = 2 * ntc * 64;
    if (t < total) {
        int l = t & 63, nt = (t >> 6) % ntc, kh = t / (ntc * 64);
        int g = l >> 4, j = l & 15;
        int n = nt * 16 + j;
        float v[8];
        #pragma unroll
        for (int ee = 0; ee < 8; ++ee) {
            int k = kh * 32 + g * 8 + ee;
            v[ee] = (n < dout) ? W[k * dout + n] : 0.f;
        }
        uint4 o;
        o.x = h2u(__floats2half2_rn(v[0], v[1]));
        o.y = h2u(__floats2half2_rn(v[2], v[3]));
        o.z = h2u(__floats2half2_rn(v[4], v[5]));
        o.w = h2u(__floats2half2_rn(v[6], v[7]));
        Wh[t] = o;
    }
}

// ---------- pass 1: bucket scatter (LDS hist -> 1 global atomic per (block,bucket) -> scatter) ----
__global__ void k_bucket2(const int* __restrict__ src, const int* __restrict__ dst,
                          int* __restrict__ bucketCnt, int* __restrict__ sorted,
                          int e, int nb, int chunk) {
    __shared__ int h[512];
    __shared__ int cur[512];
    int t = threadIdx.x;
    for (int i = t; i < nb; i += 256) h[i] = 0;
    __syncthreads();
    int b0 = blockIdx.x * chunk, b1 = min(b0 + chunk, e);
    for (int i = b0 + t; i < b1; i += 256)
        atomicAdd(&h[dst[i] >> 8], 1);
    __syncthreads();
    for (int i = t; i < nb; i += 256) {
        int cnt = h[i];
        cur[i] = cnt ? atomicAdd(&bucketCnt[i * 16], cnt) : 0;   // padded counters (64B lines)
    }
    __syncthreads();
    for (int i = b0 + t; i < b1; i += 256) {
        int d = dst[i];
        int b = d >> 8;
        int pos = atomicAdd(&cur[b], 1);
        if (pos < MAXB)
            sorted[b * MAXB + pos] = src[i] | ((d & 255) << 17);   // src < 2^17, dlow 8 bits
    }
}

// ---------- pass 2: per-bucket CSR finalize (padded layout) + degree histogram ----------
__global__ void k_csr2(const int* __restrict__ bucketCnt, const int* __restrict__ sorted,
                       int* __restrict__ eidx, int2* __restrict__ rowdeg,
                       float* __restrict__ dis, int* __restrict__ degHist, int n) {
    __shared__ int pk[MAXB];
    __shared__ int pk2[MAXB];
    __shared__ int deg[256];
    __shared__ int cur[256];
    __shared__ int wsum[4];
    __shared__ int dh[64];
    int k = blockIdx.x;
    int base = k * MAXB;
    int m = min(bucketCnt[k * 16], MAXB);
    int t = threadIdx.x;
    deg[t] = 0;
    if (t < 64) dh[t] = 0;
    __syncthreads();
    for (int j = t; j < m; j += 256) {
        int v = sorted[base + j];
        pk[j] = v;
        atomicAdd(&deg[(v >> 17) & 255], 1);
    }
    __syncthreads();
    int dv = deg[t];
    int excl = block_excl_scan<4>(dv, t, wsum);
    int node = (k << 8) + t;
    if (node < n) {
        rowdeg[node] = make_int2(base + excl, dv);
        dis[node] = rsqrtf((float)(dv + 1));   // +1 self-loop
        atomicAdd(&dh[min(dv, 63)], 1);
    }
    cur[t] = excl;
    __syncthreads();
    if (t < 64 && dh[t]) atomicAdd(&degHist[t], dh[t]);
    for (int j = t; j < m; j += 256) {
        int v = pk[j];
        int pos = atomicAdd(&cur[(v >> 17) & 255], 1);
        pk2[pos] = v & 0x1FFFF;
    }
    __syncthreads();
    for (int j = t; j < m; j += 256)
        eidx[base + j] = pk2[j];               // coalesced dump
}

// ---------- degree-group: cursor = excl-scan(degHist)  (1 wave) ----------
__global__ void k_dscan(const int* __restrict__ degHist, int* __restrict__ cursor) {
    int t = threadIdx.x;   // 64
    int v = degHist[t];
    int incl = v;
    #pragma unroll
    for (int off = 1; off < 64; off <<= 1) {
        int u = __shfl_up(incl, off, 64);
        if (t >= off) incl += u;
    }
    cursor[t] = incl - v;
}

// ---------- degree-group: perm[] = nodes grouped by degree ----------
__global__ void k_dorder(const int2* __restrict__ rowdeg, int* __restrict__ cursor,
                         int* __restrict__ perm, int n) {
    __shared__ int lh[64], lbase[64];
    int t = threadIdx.x;
    int i = blockIdx.x * 256 + t;
    if (t < 64) lh[t] = 0;
    __syncthreads();
    int bin = 0, lrank = 0;
    bool vld = i < n;
    if (vld) {
        bin = min(rowdeg[i].y, 63);
        lrank = atomicAdd(&lh[bin], 1);
    }
    __syncthreads();
    if (t < 64 && lh[t]) lbase[t] = atomicAdd(&cursor[t], lh[t]);
    __syncthreads();
    if (vld) perm[lbase[bin] + lrank] = i;
}

// ---------- MFMA GEMM (layer 1): HS2[row] = pack_f16((X[row,:64] @ W) * dis[row]) ----------
// wave = 16 rows, block = 4 waves = 64 rows. A: lane l -> row l&15, K-group l>>4.
// C: lane l, reg r -> row (l>>4)*4+r, col l&15.
template<int DOUT, int NT>
__global__ __launch_bounds__(256) void k_mfgemm(const float* __restrict__ Xv,
                                                const uint4* __restrict__ Wh,
                                                const float* __restrict__ dis,
                                                uint4* __restrict__ HS2, int n) {
    constexpr int STR = NT * 16 + 8;                  // f16 LDS row stride
    __shared__ __align__(16) _Float16 tile[4][16][STR];
    int wid = threadIdx.x >> 6, l = threadIdx.x & 63;
    int row0 = (blockIdx.x * 4 + wid) * 16;
    int g = l >> 4, j = l & 15;
    int rowA = min(row0 + j, n - 1);

    U16 bf[2][NT];
    #pragma unroll
    for (int kh = 0; kh < 2; ++kh)
        #pragma unroll
        for (int nt = 0; nt < NT; ++nt)
            bf[kh][nt].u = Wh[(kh * NT + nt) * 64 + l];

    U16 a0, a1;
    const float4* xr = (const float4*)Xv + (size_t)rowA * 16;
    float4 f0 = xr[g * 2], f1 = xr[g * 2 + 1];
    float4 f2 = xr[8 + g * 2], f3 = xr[8 + g * 2 + 1];
    a0.u.x = h2u(__floats2half2_rn(f0.x, f0.y)); a0.u.y = h2u(__floats2half2_rn(f0.z, f0.w));
    a0.u.z = h2u(__floats2half2_rn(f1.x, f1.y)); a0.u.w = h2u(__floats2half2_rn(f1.z, f1.w));
    a1.u.x = h2u(__floats2half2_rn(f2.x, f2.y)); a1.u.y = h2u(__floats2half2_rn(f2.z, f2.w));
    a1.u.z = h2u(__floats2half2_rn(f3.x, f3.y)); a1.u.w = h2u(__floats2half2_rn(f3.z, f3.w));

    f32x4 acc[NT];
    #pragma unroll
    for (int nt = 0; nt < NT; ++nt) acc[nt] = (f32x4){0.f, 0.f, 0.f, 0.f};
    #pragma unroll
    for (int nt = 0; nt < NT; ++nt) {
        acc[nt] = __builtin_amdgcn_mfma_f32_16x16x32_f16(a0.h, bf[0][nt].h, acc[nt], 0, 0, 0);
        acc[nt] = __builtin_amdgcn_mfma_f32_16x16x32_f16(a1.h, bf[1][nt].h, acc[nt], 0, 0, 0);
    }

    float4 d4 = *(const float4*)(dis + row0 + g * 4);
    float dd[4] = {d4.x, d4.y, d4.z, d4.w};
    #pragma unroll
    for (int nt = 0; nt < NT; ++nt)
        #pragma unroll
        for (int r = 0; r < 4; ++r)
            tile[wid][g * 4 + r][nt * 16 + j] = (_Float16)(acc[nt][r] * dd[r]);
    __builtin_amdgcn_wave_barrier();
    constexpr int C8 = DOUT / 8;
    #pragma unroll
    for (int idx = 0; idx < (16 * C8 + 63) / 64; ++idx) {
        int ii = idx * 64 + l;
        if (ii < 16 * C8) {
            int rr = ii / C8, c = ii % C8;
            if (row0 + rr < n) {
                uint4 v = *(const uint4*)((const char*)&tile[wid][rr][0] + c * 16);
                HS2[(size_t)(row0 + rr) * C8 + c] = v;
            }
        }
    }
}

// ---------- fused gather + GEMM: block = 16 degree-grouped nodes ----------
// Gathers 64-ch rows from tbl (4 nodes/wave), relu(agg+b) -> LDS A-tile,
// one 16-row MFMA tile (wave w = nt w), scale by dis, dump packed f16 rows.
// Output table rows padded to OSTR uint4 (layer-3: 8 = 128B lines).
template<int DOUT, int NT>
__global__ __launch_bounds__(256) void k_fgg(const int2* __restrict__ rowdeg,
                                             const int* __restrict__ eidx,
                                             const int* __restrict__ perm,
                                             const uint4* __restrict__ tbl,
                                             const float* __restrict__ dis,
                                             const float* __restrict__ bias,
                                             const uint4* __restrict__ Wh,
                                             uint4* __restrict__ outTbl, int n) {
    __shared__ __align__(16) uint4 At[16][9];               // A tile (f16, +1 pad)
    constexpr int CSTR = NT * 16 + 8;                       // f16, 16B-multiple
    __shared__ __align__(16) _Float16 Ct[16][CSTR];
    __shared__ int   smNode[16];
    __shared__ float smDis[16];
    int tid = threadIdx.x, wid = tid >> 6, lane = tid & 63;
    int nn = lane >> 4, q = (lane >> 3) & 1, c = lane & 7;
    int j16 = wid * 4 + nn;
    int pos = blockIdx.x * 16 + j16;
    bool vld = pos < n;
    int node = vld ? perm[pos] : 0;
    int2 rd = rowdeg[node];
    int s0 = rd.x;
    int d = vld ? rd.y : 0;
    float ds = dis[node];
    const float4* bp = (const float4*)(bias + 8 * c);
    float4 bA = bp[0], bB = bp[1];
    __half2 a0 = u2h(0u), a1 = u2h(0u), a2 = u2h(0u), a3 = u2h(0u);
    if (q == 0 && vld) {                        // self-loop term
        uint4 v = tbl[(unsigned)node * 8 + c];
        a0 = u2h(v.x); a1 = u2h(v.y); a2 = u2h(v.z); a3 = u2h(v.w);
    }
    const int* ep = eidx + s0;
    int k = 0;
    for (; k + 8 <= d; k += 8) {
        int e0 = ep[k + q], e1 = ep[k + 2 + q], e2 = ep[k + 4 + q], e3 = ep[k + 6 + q];
        uint4 v0 = tbl[(unsigned)e0 * 8 + c];
        uint4 v1 = tbl[(unsigned)e1 * 8 + c];
        uint4 v2 = tbl[(unsigned)e2 * 8 + c];
        uint4 v3 = tbl[(unsigned)e3 * 8 + c];
        a0 = __hadd2(a0, u2h(v0.x)); a1 = __hadd2(a1, u2h(v0.y));
        a2 = __hadd2(a2, u2h(v0.z)); a3 = __hadd2(a3, u2h(v0.w));
        a0 = __hadd2(a0, u2h(v1.x)); a1 = __hadd2(a1, u2h(v1.y));
        a2 = __hadd2(a2, u2h(v1.z)); a3 = __hadd2(a3, u2h(v1.w));
        a0 = __hadd2(a0, u2h(v2.x)); a1 = __hadd2(a1, u2h(v2.y));
        a2 = __hadd2(a2, u2h(v2.z)); a3 = __hadd2(a3, u2h(v2.w));
        a0 = __hadd2(a0, u2h(v3.x)); a1 = __hadd2(a1, u2h(v3.y));
        a2 = __hadd2(a2, u2h(v3.z)); a3 = __hadd2(a3, u2h(v3.w));
    }
    for (; k + 4 <= d; k += 4) {
        int e0 = ep[k + q], e1 = ep[k + 2 + q];
        uint4 v0 = tbl[(unsigned)e0 * 8 + c];
        uint4 v1 = tbl[(unsigned)e1 * 8 + c];
        a0 = __hadd2(a0, u2h(v0.x)); a1 = __hadd2(a1, u2h(v0.y));
        a2 = __hadd2(a2, u2h(v0.z)); a3 = __hadd2(a3, u2h(v0.w));
        a0 = __hadd2(a0, u2h(v1.x)); a1 = __hadd2(a1, u2h(v1.y));
        a2 = __hadd2(a2, u2h(v1.z)); a3 = __hadd2(a3, u2h(v1.w));
    }
    {
        int i0 = k + q, i1 = k + 2 + q;
        if (i0 < d) {
            uint4 v = tbl[(unsigned)ep[i0] * 8 + c];
            a0 = __hadd2(a0, u2h(v.x)); a1 = __hadd2(a1, u2h(v.y));
            a2 = __hadd2(a2, u2h(v.z)); a3 = __hadd2(a3, u2h(v.w));
        }
        if (i1 < d) {
            uint4 v = tbl[(unsigned)ep[i1] * 8 + c];
            a0 = __hadd2(a0, u2h(v.x)); a1 = __hadd2(a1, u2h(v.y));
            a2 = __hadd2(a2, u2h(v.z)); a3 = __hadd2(a3, u2h(v.w));
        }
    }
    unsigned w0 = h2u(a0), w1 = h2u(a1), w2 = h2u(a2), w3 = h2u(a3);
    w0 = h2u(__hadd2(u2h(w0), u2h((unsigned)__shfl_xor((int)w0, 8, 64))));
    w1 = h2u(__hadd2(u2h(w1), u2h((unsigned)__shfl_xor((int)w1, 8, 64))));
    w2 = h2u(__hadd2(u2h(w2), u2h((unsigned)__shfl_xor((int)w2, 8, 64))));
    w3 = h2u(__hadd2(u2h(w3), u2h((unsigned)__shfl_xor((int)w3, 8, 64))));
    if (q == 0) {
        float2 f0 = __half22float2(u2h(w0));
        float2 f1 = __half22float2(u2h(w1));
        float2 f2 = __half22float2(u2h(w2));
        float2 f3 = __half22float2(u2h(w3));
        float v0 = fmaxf(f0.x * ds + bA.x, 0.f), v1 = fmaxf(f0.y * ds + bA.y, 0.f);
        float v2 = fmaxf(f1.x * ds + bA.z, 0.f), v3 = fmaxf(f1.y * ds + bA.w, 0.f);
        float v4 = fmaxf(f2.x * ds + bB.x, 0.f), v5 = fmaxf(f2.y * ds + bB.y, 0.f);
        float v6 = fmaxf(f3.x * ds + bB.z, 0.f), v7 = fmaxf(f3.y * ds + bB.w, 0.f);
        uint4 o;
        o.x = h2u(__floats2half2_rn(v0, v1));
        o.y = h2u(__floats2half2_rn(v2, v3));
        o.z = h2u(__floats2half2_rn(v4, v5));
        o.w = h2u(__floats2half2_rn(v6, v7));
        At[j16][c] = o;
        if (c == 0) { smNode[j16] = vld ? node : -1; smDis[j16] = ds; }
    }
    __syncthreads();
    // MFMA phase: wave w -> nt=w
    int g = lane >> 4, jj = lane & 15;
    U16 fa0, fa1;
    fa0.u = At[jj][g];
    fa1.u = At[jj][4 + g];
    f32x4 acc = (f32x4){0.f, 0.f, 0.f, 0.f};
    if (wid < NT) {
        U16 fb0, fb1;
        fb0.u = Wh[(0 * NT + wid) * 64 + lane];
        fb1.u = Wh[(1 * NT + wid) * 64 + lane];
        acc = __builtin_amdgcn_mfma_f32_16x16x32_f16(fa0.h, fb0.h, acc, 0, 0, 0);
        acc = __builtin_amdgcn_mfma_f32_16x16x32_f16(fa1.h, fb1.h, acc, 0, 0, 0);
        #pragma unroll
        for (int r = 0; r < 4; ++r)
            Ct[g * 4 + r][wid * 16 + jj] = (_Float16)(acc[r] * smDis[g * 4 + r]);
    }
    __syncthreads();
    constexpr int C8o = DOUT / 8;
    constexpr int OSTR = (DOUT == 40) ? 8 : C8o;        // pad layer-3 rows to 128B
    if (tid < 16 * C8o) {
        int j = tid / C8o, cc = tid % C8o;
        int nd = smNode[j];
        if (nd >= 0) {
            uint4 v = *(const uint4*)((const char*)&Ct[j][0] + cc * 16);
            outTbl[(unsigned)nd * OSTR + cc] = v;
        }
    }
}

// ---------- final gather: 4 nodes/wave + fused log_softmax (40 ch, 128B-padded table) ----------
template<int DOUT>
__global__ __launch_bounds__(256) void k_gather4(const int2* __restrict__ rowdeg,
                                                 const int* __restrict__ eidx,
                                                 const int* __restrict__ perm,
                                                 const uint4* __restrict__ tbl,
                                                 const float* __restrict__ dis,
                                                 const float* __restrict__ b,
                                                 float* __restrict__ outp, int n) {
    constexpr int C8 = DOUT / 8;                 // used slots (5)
    constexpr int TSTR = (DOUT == 40) ? 8 : C8;  // row stride in uint4 (128B-padded)
    int wave = (blockIdx.x * blockDim.x + threadIdx.x) >> 6;
    int lane = threadIdx.x & 63;
    int nn = lane >> 4, q = (lane >> 3) & 1, c = lane & 7;
    int pos = wave * 4 + nn;
    bool vld = pos < n;
    int node = vld ? perm[pos] : 0;
    int2 rd = rowdeg[node];
    int s0 = rd.x;
    int d = vld ? rd.y : 0;
    bool act = vld && (c < C8);
    float ds = dis[node];
    float4 bA = make_float4(0.f, 0.f, 0.f, 0.f), bB = bA;
    if (act) {
        const float4* bp = (const float4*)(b + 8 * c);
        bA = bp[0]; bB = bp[1];
    }
    __half2 a0 = u2h(0u), a1 = u2h(0u), a2 = u2h(0u), a3 = u2h(0u);
    if (q == 0 && act) {
        uint4 v = tbl[(unsigned)node * TSTR + c];
        a0 = u2h(v.x); a1 = u2h(v.y); a2 = u2h(v.z); a3 = u2h(v.w);
    }
    const int* ep = eidx + s0;
    int k = 0;
    for (; k + 8 <= d; k += 8) {
        int e0 = ep[k + q], e1 = ep[k + 2 + q], e2 = ep[k + 4 + q], e3 = ep[k + 6 + q];
        if (act) {
            uint4 v0 = tbl[(unsigned)e0 * TSTR + c];
            uint4 v1 = tbl[(unsigned)e1 * TSTR + c];
            uint4 v2 = tbl[(unsigned)e2 * TSTR + c];
            uint4 v3 = tbl[(unsigned)e3 * TSTR + c];
            a0 = __hadd2(a0, u2h(v0.x)); a1 = __hadd2(a1, u2h(v0.y));
            a2 = __hadd2(a2, u2h(v0.z)); a3 = __hadd2(a3, u2h(v0.w));
            a0 = __hadd2(a0, u2h(v1.x)); a1 = __hadd2(a1, u2h(v1.y));
            a2 = __hadd2(a2, u2h(v1.z)); a3 = __hadd2(a3, u2h(v1.w));
            a0 = __hadd2(a0, u2h(v2.x)); a1 = __hadd2(a1, u2h(v2.y));
            a2 = __hadd2(a2, u2h(v2.z)); a3 = __hadd2(a3, u2h(v2.w));
            a0 = __hadd2(a0, u2h(v3.x)); a1 = __hadd2(a1, u2h(v3.y));
            a2 = __hadd2(a2, u2h(v3.z)); a3 = __hadd2(a3, u2h(v3.w));
        }
    }
    for (; k + 4 <= d; k += 4) {
        int e0 = ep[k + q], e1 = ep[k + 2 + q];
        if (act) {
            uint4 v0 = tbl[(unsigned)e0 * TSTR + c];
            uint4 v1 = tbl[(unsigned)e1 * TSTR + c];
            a0 = __hadd2(a0, u2h(v0.x)); a1 = __hadd2(a1, u2h(v0.y));
            a2 = __hadd2(a2, u2h(v0.z)); a3 = __hadd2(a3, u2h(v0.w));
            a0 = __hadd2(a0, u2h(v1.x)); a1 = __hadd2(a1, u2h(v1.y));
            a2 = __hadd2(a2, u2h(v1.z)); a3 = __hadd2(a3, u2h(v1.w));
        }
    }
    {
        int i0 = k + q, i1 = k + 2 + q;
        if (act && i0 < d) {
            uint4 v = tbl[(unsigned)ep[i0] * TSTR + c];
            a0 = __hadd2(a0, u2h(v.x)); a1 = __hadd2(a1, u2h(v.y));
            a2 = __hadd2(a2, u2h(v.z)); a3 = __hadd2(a3, u2h(v.w));
        }
        if (act && i1 < d) {
            uint4 v = tbl[(unsigned)ep[i1] * TSTR + c];
            a0 = __hadd2(a0, u2h(v.x)); a1 = __hadd2(a1, u2h(v.y));
            a2 = __hadd2(a2, u2h(v.z)); a3 = __hadd2(a3, u2h(v.w));
        }
    }
    unsigned w0 = h2u(a0), w1 = h2u(a1), w2 = h2u(a2), w3 = h2u(a3);
    w0 = h2u(__hadd2(u2h(w0), u2h((unsigned)__shfl_xor((int)w0, 8, 64))));
    w1 = h2u(__hadd2(u2h(w1), u2h((unsigned)__shfl_xor((int)w1, 8, 64))));
    w2 = h2u(__hadd2(u2h(w2), u2h((unsigned)__shfl_xor((int)w2, 8, 64))));
    w3 = h2u(__hadd2(u2h(w3), u2h((unsigned)__shfl_xor((int)w3, 8, 64))));
    float2 f0 = __half22float2(u2h(w0));
    float2 f1 = __half22float2(u2h(w1));
    float2 f2 = __half22float2(u2h(w2));
    float2 f3 = __half22float2(u2h(w3));
    float v0 = f0.x * ds + bA.x, v1 = f0.y * ds + bA.y;
    float v2 = f1.x * ds + bA.z, v3 = f1.y * ds + bA.w;
    float v4 = f2.x * ds + bB.x, v5 = f2.y * ds + bB.y;
    float v6 = f3.x * ds + bB.z, v7 = f3.y * ds + bB.w;
    float m = act ? fmaxf(fmaxf(fmaxf(v0, v1), fmaxf(v2, v3)),
                          fmaxf(fmaxf(v4, v5), fmaxf(v6, v7))) : -INFINITY;
    #pragma unroll
    for (int off = 1; off <= 4; off <<= 1) m = fmaxf(m, __shfl_xor(m, off, 64));
    float s = act ? (__expf(v0 - m) + __expf(v1 - m) + __expf(v2 - m) + __expf(v3 - m) +
                     __expf(v4 - m) + __expf(v5 - m) + __expf(v6 - m) + __expf(v7 - m)) : 0.f;
    #pragma unroll
    for (int off = 1; off <= 4; off <<= 1) s += __shfl_xor(s, off, 64);
    float ls = __logf(s);
    if (q == 0 && act) {
        float* op = outp + (size_t)node * DOUT + 8 * c;
        *(float4*)op = make_float4(v0 - m - ls, v1 - m - ls, v2 - m - ls, v3 - m - ls);
        *(float4*)(op + 4) = make_float4(v4 - m - ls, v5 - m - ls, v6 - m - ls, v7 - m - ls);
    }
}

extern "C" void kernel_launch(void* const* d_in, const int* in_sizes, int n_in,
                              void* d_out, int out_size, void* d_ws, size_t ws_size,
                              hipStream_t stream) {
    const float* x  = (const float*)d_in[0];
    const int*   ei = (const int*)d_in[1];
    const float* W1 = (const float*)d_in[2];
    const float* b1 = (const float*)d_in[3];
    const float* W2 = (const float*)d_in[4];
    const float* b2 = (const float*)d_in[5];
    const float* W3 = (const float*)d_in[6];
    const float* b3 = (const float*)d_in[7];
    float* out = (float*)d_out;

    const int N = in_sizes[0] / 64;
    const int E = in_sizes[1] / 2;
    const int* src = ei;
    const int* dst = ei + E;
    const int NB = (N + 255) >> 8;          // buckets
    const int CHUNK = (E + NBLK - 1) / NBLK;

    // workspace layout
    char* ws = (char*)d_ws;
    size_t off = 0;
    int2*     rowdeg     = (int2*)(ws + off);     off = align256(off + (size_t)N * 8);
    float*    dis        = (float*)(ws + off);    off = align256(off + (size_t)N * 4);
    int*      bucketCnt  = (int*)(ws + off);      off = align256(off + (size_t)NB * 16 * 4);
    int*      degHist    = (int*)(ws + off);      off = align256(off + 64 * 4);
    int*      cursor     = (int*)(ws + off);      off = align256(off + 64 * 4);
    int*      perm       = (int*)(ws + off);      off = align256(off + (size_t)N * 4);
    uint4*    Wh1        = (uint4*)(ws + off);    off = align256(off + 512 * 16);
    uint4*    Wh2        = (uint4*)(ws + off);    off = align256(off + 512 * 16);
    uint4*    Wh3        = (uint4*)(ws + off);    off = align256(off + 384 * 16);
    int*      eidx       = (int*)(ws + off);      off = align256(off + (size_t)NB * MAXB * 4);
    uint4*    hsA        = (uint4*)(ws + off);    off = align256(off + (size_t)N * 32 * 4);
    uint4*    hsB        = (uint4*)(ws + off);    off = align256(off + (size_t)N * 32 * 4);
    // aliases: sorted dead before hsB first written; hsA40 reuses hsA after it's consumed.
    int*   sorted = (int*)hsB;                        // NB*MAXB ints (9.6MB <= 12.8MB)
    uint4* hsA40  = hsA;                              // layer-3 table (N*8 uint4, 128B rows)
    (void)ws_size; (void)n_in; (void)out_size;

    const int B = 256;
    auto cdiv = [](long a, long b) { return (int)((a + b - 1) / b); };

    // ---- build: zero+wprep -> bucket scatter -> padded CSR -> degree grouping ----
    k_zero<<<4, 512, 0, stream>>>(W1, W2, W3, Wh1, Wh2, Wh3, bucketCnt, degHist, NB);
    k_bucket2<<<NBLK, B, 0, stream>>>(src, dst, bucketCnt, sorted, E, NB, CHUNK);
    k_csr2<<<NB, B, 0, stream>>>(bucketCnt, sorted, eidx, rowdeg, dis, degHist, N);
    k_dscan<<<1, 64, 0, stream>>>(degHist, cursor);
    k_dorder<<<NB, B, 0, stream>>>(rowdeg, cursor, perm, N);

    const int GG   = cdiv(N, 64);                      // mfgemm grid
    const int GFGG = cdiv(N, 16);                      // fused gather+gemm grid
    const int GATH = cdiv((long)cdiv(N, 4) * 64, B);   // final gather grid

    // ---- layer 1 GEMM: x @ W1 * dis -> hsA ----
    k_mfgemm<64, 4><<<GG, B, 0, stream>>>(x, Wh1, dis, hsA, N);
    // ---- layer 1 aggregate + relu + layer 2 GEMM -> hsB ----
    k_fgg<64, 4><<<GFGG, B, 0, stream>>>(rowdeg, eidx, perm, hsA, dis, b1, Wh2, hsB, N);
    // ---- layer 2 aggregate + relu + layer 3 GEMM -> hsA40 (128B-padded rows) ----
    k_fgg<40, 3><<<GFGG, B, 0, stream>>>(rowdeg, eidx, perm, hsB, dis, b2, Wh3, hsA40, N);
    // ---- layer 3 aggregate + bias + log_softmax -> out ----
    k_gather4<40><<<GATH, B, 0, stream>>>(rowdeg, eidx, perm, hsA40, dis, b3, out, N);
}

// Round 12
// 157.035 us; speedup vs baseline: 1.1733x; 1.1733x over previous
//
#include <hip/hip_runtime.h>
#include <hip/hip_fp16.h>
#include <math.h>

// GCN 3-layer forward. Padded-CSR gather (f16 tables), MFMA GEMMs, fused gather+GEMM.
// out[i] = dis[i]*(hs[i] + sum_{src in N(i)} hs[src]) + b,  hs = (act(X)@W)*dis[row]

static inline size_t align256(size_t x) { return (x + 255) & ~(size_t)255; }

#define NBLK 512          // blocks for bucket pass (sets write-run length: chunk/NB ~ 8)
#define BTHR 1024         // threads per bucket block (16 waves: latency hiding)
#define MAXB 6144         // fixed bucket capacity (mean 4092, sigma 64 -> +32 sigma)

using f16x8 = __attribute__((ext_vector_type(8))) _Float16;
using f32x4 = __attribute__((ext_vector_type(4))) float;
union U16 { uint4 u; f16x8 h; };

__device__ __forceinline__ __half2 u2h(unsigned u) { union { unsigned u; __half2 h; } t; t.u = u; return t.h; }
__device__ __forceinline__ unsigned h2u(__half2 h) { union { unsigned u; __half2 h; } t; t.h = h; return t.u; }

// exclusive scan of one value per thread across the block (256 threads)
template<int NW>
__device__ __forceinline__ int block_excl_scan(int v, int t, int* wsum) {
    int lane = t & 63, w = t >> 6;
    int incl = v;
    #pragma unroll
    for (int off = 1; off < 64; off <<= 1) {
        int u = __shfl_up(incl, off, 64);
        if (lane >= off) incl += u;
    }
    if (lane == 63) wsum[w] = incl;
    __syncthreads();
    if (t == 0) {
        int acc = 0;
        #pragma unroll
        for (int i = 0; i < NW; ++i) { int x = wsum[i]; wsum[i] = acc; acc += x; }
    }
    __syncthreads();
    return incl - v + wsum[w];
}

// ---------- pass 0: weight prep (blocks 0..2) + zero counters (block 3) ----------
__global__ void k_zero(const float* __restrict__ W1, const float* __restrict__ W2,
                       const float* __restrict__ W3, uint4* __restrict__ Wh1,
                       uint4* __restrict__ Wh2, uint4* __restrict__ Wh3,
                       int* __restrict__ bucketCnt, int* __restrict__ degHist, int nb) {
    int b = blockIdx.x;
    int t = threadIdx.x;
    if (b == 3) {
        for (int i = t; i < nb * 16; i += 512) bucketCnt[i] = 0;
        if (t < 64) degHist[t] = 0;
        return;
    }
    const float* W = (b == 0) ? W1 : (b == 1) ? W2 : W3;
    uint4* Wh = (b == 0) ? Wh1 : (b == 1) ? Wh2 : Wh3;
    int dout = (b == 2) ? 40 : 64, ntc = (b == 2) ? 3 : 4;
    int total = 2 * ntc * 64;
    if (t < total) {
        int l = t & 63, nt = (t >> 6) % ntc, kh = t / (ntc * 64);
        int g = l >> 4, j = l & 15;
        int n = nt * 16 + j;
        float v[8];
        #pragma unroll
        for (int ee = 0; ee < 8; ++ee) {
            int k = kh * 32 + g * 8 + ee;
            v[ee] = (n < dout) ? W[k * dout + n] : 0.f;
        }
        uint4 o;
        o.x = h2u(__floats2half2_rn(v[0], v[1]));
        o.y = h2u(__floats2half2_rn(v[2], v[3]));
        o.z = h2u(__floats2half2_rn(v[4], v[5]));
        o.w = h2u(__floats2half2_rn(v[6], v[7]));
        Wh[t] = o;
    }
}

// ---------- pass 1: bucket scatter (LDS hist -> 1 global atomic per (block,bucket) -> scatter) ----
// 512 blocks (write-run length 8) x 16 waves (latency hiding).
__global__ __launch_bounds__(BTHR) void k_bucket2(const int* __restrict__ src,
                                                  const int* __restrict__ dst,
                                                  int* __restrict__ bucketCnt,
                                                  int* __restrict__ sorted,
                                                  int e, int nb, int chunk) {
    __shared__ int h[512];
    __shared__ int cur[512];
    int t = threadIdx.x;
    for (int i = t; i < nb; i += BTHR) h[i] = 0;
    __syncthreads();
    int b0 = blockIdx.x * chunk, b1 = min(b0 + chunk, e);
    for (int i = b0 + t; i < b1; i += BTHR)
        atomicAdd(&h[dst[i] >> 8], 1);
    __syncthreads();
    for (int i = t; i < nb; i += BTHR) {
        int cnt = h[i];
        cur[i] = cnt ? atomicAdd(&bucketCnt[i * 16], cnt) : 0;   // padded counters (64B lines)
    }
    __syncthreads();
    for (int i = b0 + t; i < b1; i += BTHR) {
        int d = dst[i];
        int b = d >> 8;
        int pos = atomicAdd(&cur[b], 1);
        if (pos < MAXB)
            sorted[b * MAXB + pos] = src[i] | ((d & 255) << 17);   // src < 2^17, dlow 8 bits
    }
}

// ---------- pass 2: per-bucket CSR finalize (padded layout) + degree histogram ----------
__global__ void k_csr2(const int* __restrict__ bucketCnt, const int* __restrict__ sorted,
                       int* __restrict__ eidx, int2* __restrict__ rowdeg,
                       float* __restrict__ dis, int* __restrict__ degHist, int n) {
    __shared__ int pk[MAXB];
    __shared__ int pk2[MAXB];
    __shared__ int deg[256];
    __shared__ int cur[256];
    __shared__ int wsum[4];
    __shared__ int dh[64];
    int k = blockIdx.x;
    int base = k * MAXB;
    int m = min(bucketCnt[k * 16], MAXB);
    int t = threadIdx.x;
    deg[t] = 0;
    if (t < 64) dh[t] = 0;
    __syncthreads();
    for (int j = t; j < m; j += 256) {
        int v = sorted[base + j];
        pk[j] = v;
        atomicAdd(&deg[(v >> 17) & 255], 1);
    }
    __syncthreads();
    int dv = deg[t];
    int excl = block_excl_scan<4>(dv, t, wsum);
    int node = (k << 8) + t;
    if (node < n) {
        rowdeg[node] = make_int2(base + excl, dv);
        dis[node] = rsqrtf((float)(dv + 1));   // +1 self-loop
        atomicAdd(&dh[min(dv, 63)], 1);
    }
    cur[t] = excl;
    __syncthreads();
    if (t < 64 && dh[t]) atomicAdd(&degHist[t], dh[t]);
    for (int j = t; j < m; j += 256) {
        int v = pk[j];
        int pos = atomicAdd(&cur[(v >> 17) & 255], 1);
        pk2[pos] = v & 0x1FFFF;
    }
    __syncthreads();
    for (int j = t; j < m; j += 256)
        eidx[base + j] = pk2[j];               // coalesced dump
}

// ---------- degree-group: cursor = excl-scan(degHist)  (1 wave) ----------
__global__ void k_dscan(const int* __restrict__ degHist, int* __restrict__ cursor) {
    int t = threadIdx.x;   // 64
    int v = degHist[t];
    int incl = v;
    #pragma unroll
    for (int off = 1; off < 64; off <<= 1) {
        int u = __shfl_up(incl, off, 64);
        if (t >= off) incl += u;
    }
    cursor[t] = incl - v;
}

// ---------- degree-group: perm[] = nodes grouped by degree ----------
__global__ void k_dorder(const int2* __restrict__ rowdeg, int* __restrict__ cursor,
                         int* __restrict__ perm, int n) {
    __shared__ int lh[64], lbase[64];
    int t = threadIdx.x;
    int i = blockIdx.x * 256 + t;
    if (t < 64) lh[t] = 0;
    __syncthreads();
    int bin = 0, lrank = 0;
    bool vld = i < n;
    if (vld) {
        bin = min(rowdeg[i].y, 63);
        lrank = atomicAdd(&lh[bin], 1);
    }
    __syncthreads();
    if (t < 64 && lh[t]) lbase[t] = atomicAdd(&cursor[t], lh[t]);
    __syncthreads();
    if (vld) perm[lbase[bin] + lrank] = i;
}

// ---------- MFMA GEMM (layer 1): HS2[row] = pack_f16((X[row,:64] @ W) * dis[row]) ----------
// wave = 16 rows, block = 4 waves = 64 rows. A: lane l -> row l&15, K-group l>>4.
// C: lane l, reg r -> row (l>>4)*4+r, col l&15.
template<int DOUT, int NT>
__global__ __launch_bounds__(256) void k_mfgemm(const float* __restrict__ Xv,
                                                const uint4* __restrict__ Wh,
                                                const float* __restrict__ dis,
                                                uint4* __restrict__ HS2, int n) {
    constexpr int STR = NT * 16 + 8;                  // f16 LDS row stride
    __shared__ __align__(16) _Float16 tile[4][16][STR];
    int wid = threadIdx.x >> 6, l = threadIdx.x & 63;
    int row0 = (blockIdx.x * 4 + wid) * 16;
    int g = l >> 4, j = l & 15;
    int rowA = min(row0 + j, n - 1);

    U16 bf[2][NT];
    #pragma unroll
    for (int kh = 0; kh < 2; ++kh)
        #pragma unroll
        for (int nt = 0; nt < NT; ++nt)
            bf[kh][nt].u = Wh[(kh * NT + nt) * 64 + l];

    U16 a0, a1;
    const float4* xr = (const float4*)Xv + (size_t)rowA * 16;
    float4 f0 = xr[g * 2], f1 = xr[g * 2 + 1];
    float4 f2 = xr[8 + g * 2], f3 = xr[8 + g * 2 + 1];
    a0.u.x = h2u(__floats2half2_rn(f0.x, f0.y)); a0.u.y = h2u(__floats2half2_rn(f0.z, f0.w));
    a0.u.z = h2u(__floats2half2_rn(f1.x, f1.y)); a0.u.w = h2u(__floats2half2_rn(f1.z, f1.w));
    a1.u.x = h2u(__floats2half2_rn(f2.x, f2.y)); a1.u.y = h2u(__floats2half2_rn(f2.z, f2.w));
    a1.u.z = h2u(__floats2half2_rn(f3.x, f3.y)); a1.u.w = h2u(__floats2half2_rn(f3.z, f3.w));

    f32x4 acc[NT];
    #pragma unroll
    for (int nt = 0; nt < NT; ++nt) acc[nt] = (f32x4){0.f, 0.f, 0.f, 0.f};
    #pragma unroll
    for (int nt = 0; nt < NT; ++nt) {
        acc[nt] = __builtin_amdgcn_mfma_f32_16x16x32_f16(a0.h, bf[0][nt].h, acc[nt], 0, 0, 0);
        acc[nt] = __builtin_amdgcn_mfma_f32_16x16x32_f16(a1.h, bf[1][nt].h, acc[nt], 0, 0, 0);
    }

    float4 d4 = *(const float4*)(dis + row0 + g * 4);
    float dd[4] = {d4.x, d4.y, d4.z, d4.w};
    #pragma unroll
    for (int nt = 0; nt < NT; ++nt)
        #pragma unroll
        for (int r = 0; r < 4; ++r)
            tile[wid][g * 4 + r][nt * 16 + j] = (_Float16)(acc[nt][r] * dd[r]);
    __builtin_amdgcn_wave_barrier();
    constexpr int C8 = DOUT / 8;
    #pragma unroll
    for (int idx = 0; idx < (16 * C8 + 63) / 64; ++idx) {
        int ii = idx * 64 + l;
        if (ii < 16 * C8) {
            int rr = ii / C8, c = ii % C8;
            if (row0 + rr < n) {
                uint4 v = *(const uint4*)((const char*)&tile[wid][rr][0] + c * 16);
                HS2[(size_t)(row0 + rr) * C8 + c] = v;
            }
        }
    }
}

// ---------- fused gather + GEMM: block = 16 degree-grouped nodes ----------
// Gathers 64-ch rows from tbl (4 nodes/wave), relu(agg+b) -> LDS A-tile,
// one 16-row MFMA tile (wave w = nt w), scale by dis, dump packed f16 rows.
// Output table rows padded to OSTR uint4 (layer-3: 8 = 128B lines).
template<int DOUT, int NT>
__global__ __launch_bounds__(256) void k_fgg(const int2* __restrict__ rowdeg,
                                             const int* __restrict__ eidx,
                                             const int* __restrict__ perm,
                                             const uint4* __restrict__ tbl,
                                             const float* __restrict__ dis,
                                             const float* __restrict__ bias,
                                             const uint4* __restrict__ Wh,
                                             uint4* __restrict__ outTbl, int n) {
    __shared__ __align__(16) uint4 At[16][9];               // A tile (f16, +1 pad)
    constexpr int CSTR = NT * 16 + 8;                       // f16, 16B-multiple
    __shared__ __align__(16) _Float16 Ct[16][CSTR];
    __shared__ int   smNode[16];
    __shared__ float smDis[16];
    int tid = threadIdx.x, wid = tid >> 6, lane = tid & 63;
    int nn = lane >> 4, q = (lane >> 3) & 1, c = lane & 7;
    int j16 = wid * 4 + nn;
    int pos = blockIdx.x * 16 + j16;
    bool vld = pos < n;
    int node = vld ? perm[pos] : 0;
    int2 rd = rowdeg[node];
    int s0 = rd.x;
    int d = vld ? rd.y : 0;
    float ds = dis[node];
    const float4* bp = (const float4*)(bias + 8 * c);
    float4 bA = bp[0], bB = bp[1];
    __half2 a0 = u2h(0u), a1 = u2h(0u), a2 = u2h(0u), a3 = u2h(0u);
    if (q == 0 && vld) {                        // self-loop term
        uint4 v = tbl[(unsigned)node * 8 + c];
        a0 = u2h(v.x); a1 = u2h(v.y); a2 = u2h(v.z); a3 = u2h(v.w);
    }
    const int* ep = eidx + s0;
    int k = 0;
    for (; k + 8 <= d; k += 8) {
        int e0 = ep[k + q], e1 = ep[k + 2 + q], e2 = ep[k + 4 + q], e3 = ep[k + 6 + q];
        uint4 v0 = tbl[(unsigned)e0 * 8 + c];
        uint4 v1 = tbl[(unsigned)e1 * 8 + c];
        uint4 v2 = tbl[(unsigned)e2 * 8 + c];
        uint4 v3 = tbl[(unsigned)e3 * 8 + c];
        a0 = __hadd2(a0, u2h(v0.x)); a1 = __hadd2(a1, u2h(v0.y));
        a2 = __hadd2(a2, u2h(v0.z)); a3 = __hadd2(a3, u2h(v0.w));
        a0 = __hadd2(a0, u2h(v1.x)); a1 = __hadd2(a1, u2h(v1.y));
        a2 = __hadd2(a2, u2h(v1.z)); a3 = __hadd2(a3, u2h(v1.w));
        a0 = __hadd2(a0, u2h(v2.x)); a1 = __hadd2(a1, u2h(v2.y));
        a2 = __hadd2(a2, u2h(v2.z)); a3 = __hadd2(a3, u2h(v2.w));
        a0 = __hadd2(a0, u2h(v3.x)); a1 = __hadd2(a1, u2h(v3.y));
        a2 = __hadd2(a2, u2h(v3.z)); a3 = __hadd2(a3, u2h(v3.w));
    }
    for (; k + 4 <= d; k += 4) {
        int e0 = ep[k + q], e1 = ep[k + 2 + q];
        uint4 v0 = tbl[(unsigned)e0 * 8 + c];
        uint4 v1 = tbl[(unsigned)e1 * 8 + c];
        a0 = __hadd2(a0, u2h(v0.x)); a1 = __hadd2(a1, u2h(v0.y));
        a2 = __hadd2(a2, u2h(v0.z)); a3 = __hadd2(a3, u2h(v0.w));
        a0 = __hadd2(a0, u2h(v1.x)); a1 = __hadd2(a1, u2h(v1.y));
        a2 = __hadd2(a2, u2h(v1.z)); a3 = __hadd2(a3, u2h(v1.w));
    }
    {
        int i0 = k + q, i1 = k + 2 + q;
        if (i0 < d) {
            uint4 v = tbl[(unsigned)ep[i0] * 8 + c];
            a0 = __hadd2(a0, u2h(v.x)); a1 = __hadd2(a1, u2h(v.y));
            a2 = __hadd2(a2, u2h(v.z)); a3 = __hadd2(a3, u2h(v.w));
        }
        if (i1 < d) {
            uint4 v = tbl[(unsigned)ep[i1] * 8 + c];
            a0 = __hadd2(a0, u2h(v.x)); a1 = __hadd2(a1, u2h(v.y));
            a2 = __hadd2(a2, u2h(v.z)); a3 = __hadd2(a3, u2h(v.w));
        }
    }
    unsigned w0 = h2u(a0), w1 = h2u(a1), w2 = h2u(a2), w3 = h2u(a3);
    w0 = h2u(__hadd2(u2h(w0), u2h((unsigned)__shfl_xor((int)w0, 8, 64))));
    w1 = h2u(__hadd2(u2h(w1), u2h((unsigned)__shfl_xor((int)w1, 8, 64))));
    w2 = h2u(__hadd2(u2h(w2), u2h((unsigned)__shfl_xor((int)w2, 8, 64))));
    w3 = h2u(__hadd2(u2h(w3), u2h((unsigned)__shfl_xor((int)w3, 8, 64))));
    if (q == 0) {
        float2 f0 = __half22float2(u2h(w0));
        float2 f1 = __half22float2(u2h(w1));
        float2 f2 = __half22float2(u2h(w2));
        float2 f3 = __half22float2(u2h(w3));
        float v0 = fmaxf(f0.x * ds + bA.x, 0.f), v1 = fmaxf(f0.y * ds + bA.y, 0.f);
        float v2 = fmaxf(f1.x * ds + bA.z, 0.f), v3 = fmaxf(f1.y * ds + bA.w, 0.f);
        float v4 = fmaxf(f2.x * ds + bB.x, 0.f), v5 = fmaxf(f2.y * ds + bB.y, 0.f);
        float v6 = fmaxf(f3.x * ds + bB.z, 0.f), v7 = fmaxf(f3.y * ds + bB.w, 0.f);
        uint4 o;
        o.x = h2u(__floats2half2_rn(v0, v1));
        o.y = h2u(__floats2half2_rn(v2, v3));
        o.z = h2u(__floats2half2_rn(v4, v5));
        o.w = h2u(__floats2half2_rn(v6, v7));
        At[j16][c] = o;
        if (c == 0) { smNode[j16] = vld ? node : -1; smDis[j16] = ds; }
    }
    __syncthreads();
    // MFMA phase: wave w -> nt=w
    int g = lane >> 4, jj = lane & 15;
    U16 fa0, fa1;
    fa0.u = At[jj][g];
    fa1.u = At[jj][4 + g];
    f32x4 acc = (f32x4){0.f, 0.f, 0.f, 0.f};
    if (wid < NT) {
        U16 fb0, fb1;
        fb0.u = Wh[(0 * NT + wid) * 64 + lane];
        fb1.u = Wh[(1 * NT + wid) * 64 + lane];
        acc = __builtin_amdgcn_mfma_f32_16x16x32_f16(fa0.h, fb0.h, acc, 0, 0, 0);
        acc = __builtin_amdgcn_mfma_f32_16x16x32_f16(fa1.h, fb1.h, acc, 0, 0, 0);
        #pragma unroll
        for (int r = 0; r < 4; ++r)
            Ct[g * 4 + r][wid * 16 + jj] = (_Float16)(acc[r] * smDis[g * 4 + r]);
    }
    __syncthreads();
    constexpr int C8o = DOUT / 8;
    constexpr int OSTR = (DOUT == 40) ? 8 : C8o;        // pad layer-3 rows to 128B
    if (tid < 16 * C8o) {
        int j = tid / C8o, cc = tid % C8o;
        int nd = smNode[j];
        if (nd >= 0) {
            uint4 v = *(const uint4*)((const char*)&Ct[j][0] + cc * 16);
            outTbl[(unsigned)nd * OSTR + cc] = v;
        }
    }
}

// ---------- final gather: 4 nodes/wave + fused log_softmax (40 ch, 128B-padded table) ----------
template<int DOUT>
__global__ __launch_bounds__(256) void k_gather4(const int2* __restrict__ rowdeg,
                                                 const int* __restrict__ eidx,
                                                 const int* __restrict__ perm,
                                                 const uint4* __restrict__ tbl,
                                                 const float* __restrict__ dis,
                                                 const float* __restrict__ b,
                                                 float* __restrict__ outp, int n) {
    constexpr int C8 = DOUT / 8;                 // used slots (5)
    constexpr int TSTR = (DOUT == 40) ? 8 : C8;  // row stride in uint4 (128B-padded)
    int wave = (blockIdx.x * blockDim.x + threadIdx.x) >> 6;
    int lane = threadIdx.x & 63;
    int nn = lane >> 4, q = (lane >> 3) & 1, c = lane & 7;
    int pos = wave * 4 + nn;
    bool vld = pos < n;
    int node = vld ? perm[pos] : 0;
    int2 rd = rowdeg[node];
    int s0 = rd.x;
    int d = vld ? rd.y : 0;
    bool act = vld && (c < C8);
    float ds = dis[node];
    float4 bA = make_float4(0.f, 0.f, 0.f, 0.f), bB = bA;
    if (act) {
        const float4* bp = (const float4*)(b + 8 * c);
        bA = bp[0]; bB = bp[1];
    }
    __half2 a0 = u2h(0u), a1 = u2h(0u), a2 = u2h(0u), a3 = u2h(0u);
    if (q == 0 && act) {
        uint4 v = tbl[(unsigned)node * TSTR + c];
        a0 = u2h(v.x); a1 = u2h(v.y); a2 = u2h(v.z); a3 = u2h(v.w);
    }
    const int* ep = eidx + s0;
    int k = 0;
    for (; k + 8 <= d; k += 8) {
        int e0 = ep[k + q], e1 = ep[k + 2 + q], e2 = ep[k + 4 + q], e3 = ep[k + 6 + q];
        if (act) {
            uint4 v0 = tbl[(unsigned)e0 * TSTR + c];
            uint4 v1 = tbl[(unsigned)e1 * TSTR + c];
            uint4 v2 = tbl[(unsigned)e2 * TSTR + c];
            uint4 v3 = tbl[(unsigned)e3 * TSTR + c];
            a0 = __hadd2(a0, u2h(v0.x)); a1 = __hadd2(a1, u2h(v0.y));
            a2 = __hadd2(a2, u2h(v0.z)); a3 = __hadd2(a3, u2h(v0.w));
            a0 = __hadd2(a0, u2h(v1.x)); a1 = __hadd2(a1, u2h(v1.y));
            a2 = __hadd2(a2, u2h(v1.z)); a3 = __hadd2(a3, u2h(v1.w));
            a0 = __hadd2(a0, u2h(v2.x)); a1 = __hadd2(a1, u2h(v2.y));
            a2 = __hadd2(a2, u2h(v2.z)); a3 = __hadd2(a3, u2h(v2.w));
            a0 = __hadd2(a0, u2h(v3.x)); a1 = __hadd2(a1, u2h(v3.y));
            a2 = __hadd2(a2, u2h(v3.z)); a3 = __hadd2(a3, u2h(v3.w));
        }
    }
    for (; k + 4 <= d; k += 4) {
        int e0 = ep[k + q], e1 = ep[k + 2 + q];
        if (act) {
            uint4 v0 = tbl[(unsigned)e0 * TSTR + c];
            uint4 v1 = tbl[(unsigned)e1 * TSTR + c];
            a0 = __hadd2(a0, u2h(v0.x)); a1 = __hadd2(a1, u2h(v0.y));
            a2 = __hadd2(a2, u2h(v0.z)); a3 = __hadd2(a3, u2h(v0.w));
            a0 = __hadd2(a0, u2h(v1.x)); a1 = __hadd2(a1, u2h(v1.y));
            a2 = __hadd2(a2, u2h(v1.z)); a3 = __hadd2(a3, u2h(v1.w));
        }
    }
    {
        int i0 = k + q, i1 = k + 2 + q;
        if (act && i0 < d) {
            uint4 v = tbl[(unsigned)ep[i0] * TSTR + c];
            a0 = __hadd2(a0, u2h(v.x)); a1 = __hadd2(a1, u2h(v.y));
            a2 = __hadd2(a2, u2h(v.z)); a3 = __hadd2(a3, u2h(v.w));
        }
        if (act && i1 < d) {
            uint4 v = tbl[(unsigned)ep[i1] * TSTR + c];
            a0 = __hadd2(a0, u2h(v.x)); a1 = __hadd2(a1, u2h(v.y));
            a2 = __hadd2(a2, u2h(v.z)); a3 = __hadd2(a3, u2h(v.w));
        }
    }
    unsigned w0 = h2u(a0), w1 = h2u(a1), w2 = h2u(a2), w3 = h2u(a3);
    w0 = h2u(__hadd2(u2h(w0), u2h((unsigned)__shfl_xor((int)w0, 8, 64))));
    w1 = h2u(__hadd2(u2h(w1), u2h((unsigned)__shfl_xor((int)w1, 8, 64))));
    w2 = h2u(__hadd2(u2h(w2), u2h((unsigned)__shfl_xor((int)w2, 8, 64))));
    w3 = h2u(__hadd2(u2h(w3), u2h((unsigned)__shfl_xor((int)w3, 8, 64))));
    float2 f0 = __half22float2(u2h(w0));
    float2 f1 = __half22float2(u2h(w1));
    float2 f2 = __half22float2(u2h(w2));
    float2 f3 = __half22float2(u2h(w3));
    float v0 = f0.x * ds + bA.x, v1 = f0.y * ds + bA.y;
    float v2 = f1.x * ds + bA.z, v3 = f1.y * ds + bA.w;
    float v4 = f2.x * ds + bB.x, v5 = f2.y * ds + bB.y;
    float v6 = f3.x * ds + bB.z, v7 = f3.y * ds + bB.w;
    float m = act ? fmaxf(fmaxf(fmaxf(v0, v1), fmaxf(v2, v3)),
                          fmaxf(fmaxf(v4, v5), fmaxf(v6, v7))) : -INFINITY;
    #pragma unroll
    for (int off = 1; off <= 4; off <<= 1) m = fmaxf(m, __shfl_xor(m, off, 64));
    float s = act ? (__expf(v0 - m) + __expf(v1 - m) + __expf(v2 - m) + __expf(v3 - m) +
                     __expf(v4 - m) + __expf(v5 - m) + __expf(v6 - m) + __expf(v7 - m)) : 0.f;
    #pragma unroll
    for (int off = 1; off <= 4; off <<= 1) s += __shfl_xor(s, off, 64);
    float ls = __logf(s);
    if (q == 0 && act) {
        float* op = outp + (size_t)node * DOUT + 8 * c;
        *(float4*)op = make_float4(v0 - m - ls, v1 - m - ls, v2 - m - ls, v3 - m - ls);
        *(float4*)(op + 4) = make_float4(v4 - m - ls, v5 - m - ls, v6 - m - ls, v7 - m - ls);
    }
}

extern "C" void kernel_launch(void* const* d_in, const int* in_sizes, int n_in,
                              void* d_out, int out_size, void* d_ws, size_t ws_size,
                              hipStream_t stream) {
    const float* x  = (const float*)d_in[0];
    const int*   ei = (const int*)d_in[1];
    const float* W1 = (const float*)d_in[2];
    const float* b1 = (const float*)d_in[3];
    const float* W2 = (const float*)d_in[4];
    const float* b2 = (const float*)d_in[5];
    const float* W3 = (const float*)d_in[6];
    const float* b3 = (const float*)d_in[7];
    float* out = (float*)d_out;

    const int N = in_sizes[0] / 64;
    const int E = in_sizes[1] / 2;
    const int* src = ei;
    const int* dst = ei + E;
    const int NB = (N + 255) >> 8;          // buckets
    const int CHUNK = (E + NBLK - 1) / NBLK;

    // workspace layout
    char* ws = (char*)d_ws;
    size_t off = 0;
    int2*     rowdeg     = (int2*)(ws + off);     off = align256(off + (size_t)N * 8);
    float*    dis        = (float*)(ws + off);    off = align256(off + (size_t)N * 4);
    int*      bucketCnt  = (int*)(ws + off);      off = align256(off + (size_t)NB * 16 * 4);
    int*      degHist    = (int*)(ws + off);      off = align256(off + 64 * 4);
    int*      cursor     = (int*)(ws + off);      off = align256(off + 64 * 4);
    int*      perm       = (int*)(ws + off);      off = align256(off + (size_t)N * 4);
    uint4*    Wh1        = (uint4*)(ws + off);    off = align256(off + 512 * 16);
    uint4*    Wh2        = (uint4*)(ws + off);    off = align256(off + 512 * 16);
    uint4*    Wh3        = (uint4*)(ws + off);    off = align256(off + 384 * 16);
    int*      eidx       = (int*)(ws + off);      off = align256(off + (size_t)NB * MAXB * 4);
    uint4*    hsA        = (uint4*)(ws + off);    off = align256(off + (size_t)N * 32 * 4);
    uint4*    hsB        = (uint4*)(ws + off);    off = align256(off + (size_t)N * 32 * 4);
    // aliases: sorted dead before hsB first written; hsA40 reuses hsA after it's consumed.
    int*   sorted = (int*)hsB;                        // NB*MAXB ints (9.6MB <= 12.8MB)
    uint4* hsA40  = hsA;                              // layer-3 table (N*8 uint4, 128B rows)
    (void)ws_size; (void)n_in; (void)out_size;

    const int B = 256;
    auto cdiv = [](long a, long b) { return (int)((a + b - 1) / b); };

    // ---- build: zero+wprep -> bucket scatter -> padded CSR -> degree grouping ----
    k_zero<<<4, 512, 0, stream>>>(W1, W2, W3, Wh1, Wh2, Wh3, bucketCnt, degHist, NB);
    k_bucket2<<<NBLK, BTHR, 0, stream>>>(src, dst, bucketCnt, sorted, E, NB, CHUNK);
    k_csr2<<<NB, B, 0, stream>>>(bucketCnt, sorted, eidx, rowdeg, dis, degHist, N);
    k_dscan<<<1, 64, 0, stream>>>(degHist, cursor);
    k_dorder<<<NB, B, 0, stream>>>(rowdeg, cursor, perm, N);

    const int GG   = cdiv(N, 64);                      // mfgemm grid
    const int GFGG = cdiv(N, 16);                      // fused gather+gemm grid
    const int GATH = cdiv((long)cdiv(N, 4) * 64, B);   // final gather grid

    // ---- layer 1 GEMM: x @ W1 * dis -> hsA ----
    k_mfgemm<64, 4><<<GG, B, 0, stream>>>(x, Wh1, dis, hsA, N);
    // ---- layer 1 aggregate + relu + layer 2 GEMM -> hsB ----
    k_fgg<64, 4><<<GFGG, B, 0, stream>>>(rowdeg, eidx, perm, hsA, dis, b1, Wh2, hsB, N);
    // ---- layer 2 aggregate + relu + layer 3 GEMM -> hsA40 (128B-padded rows) ----
    k_fgg<40, 3><<<GFGG, B, 0, stream>>>(rowdeg, eidx, perm, hsB, dis, b2, Wh3, hsA40, N);
    // ---- layer 3 aggregate + bias + log_softmax -> out ----
    k_gather4<40><<<GATH, B, 0, stream>>>(rowdeg, eidx, perm, hsA40, dis, b3, out, N);
}